// Round 14
// baseline (1672.648 us; speedup 1.0000x reference)
//
#include <hip/hip_runtime.h>
#include <math.h>

// B=64, S=256, IN_DIM=512, MEM=256, LAYERS=3, HEADS=8, TOP_K=200. NROW=16384.

typedef __attribute__((ext_vector_type(8))) short s16x8;
typedef __attribute__((ext_vector_type(4))) short s16x4;
typedef __attribute__((ext_vector_type(4))) float f32x4;

__device__ __forceinline__ short f2bf(float x) {
    unsigned u = __float_as_uint(x);
    u += 0x7FFF + ((u >> 16) & 1);  // rn-even
    return (short)(u >> 16);
}
__device__ __forceinline__ float bf2f(short h) {
    return __uint_as_float(((unsigned)(unsigned short)h) << 16);
}

// async global->LDS, 16B per lane. LDS layout must be lane-contiguous (ours is).
__device__ __forceinline__ void gl2l(const void* g, void* l) {
    __builtin_amdgcn_global_load_lds(
        (const __attribute__((address_space(1))) unsigned int*)g,
        (__attribute__((address_space(3))) unsigned int*)l, 16, 0, 0);
}

__device__ __forceinline__ float blk_sum(float v, float* sb) {
#pragma unroll
    for (int o = 32; o; o >>= 1) v += __shfl_down(v, o);
    int lane = threadIdx.x & 63, w = threadIdx.x >> 6;
    if (!lane) sb[w] = v;
    __syncthreads();
    float r = sb[0] + sb[1] + sb[2] + sb[3];
    __syncthreads();
    return r;
}

__global__ void init_flags(int* flags) {
    if (threadIdx.x < 3) flags[threadIdx.x] = 0;
}

__global__ void detect_mask(const unsigned int* __restrict__ w, int nwords, int* flags) {
    int stride = gridDim.x * blockDim.x;
    int l_u8 = 0, l_f32 = 0, l_nz = 0;
    for (int i = blockIdx.x * blockDim.x + threadIdx.x; i < nwords; i += stride) {
        unsigned v = w[i];
        if (v) {
            l_nz = 1;
            if (v == 0x3F800000u) l_f32 = 1;
            else if (v > 1u) l_u8 = 1;
        }
    }
    if (__ballot(l_u8) && (threadIdx.x & 63) == 0) atomicOr(&flags[0], 1);
    if (__ballot(l_f32) && (threadIdx.x & 63) == 0) atomicOr(&flags[1], 1);
    if (__ballot(l_nz) && (threadIdx.x & 63) == 0) atomicOr(&flags[2], 1);
}

__global__ void extract_pad(const void* __restrict__ mask, const int* __restrict__ flags,
                            unsigned char* __restrict__ pad) {
    int b = blockIdx.x, i = threadIdx.x;
    int v;
    size_t idx = (size_t)b * 65536 + (size_t)i * 256;
    if (flags[0]) v = ((const unsigned char*)mask)[idx] != 0;
    else if (flags[2]) v = ((const unsigned int*)mask)[idx] != 0;
    else v = 0;
    pad[b * 256 + i] = (unsigned char)v;
}

__global__ void rowsum_plus1(const float* __restrict__ x, float* __restrict__ out) {
    __shared__ float sb[4];
    int row = blockIdx.x;
    float v = x[(size_t)row * 256 + threadIdx.x];
    float r = blk_sum(v, sb);
    if (!threadIdx.x) out[row] = r + 1.f;
}

__global__ void split_mat(const float* __restrict__ src, int ldsrc, int width,
                          short* __restrict__ dh, short* __restrict__ dl, int ldd) {
    int row = blockIdx.x;
    for (int c = threadIdx.x; c < width; c += 256) {
        float v = src[(size_t)row * ldsrc + c];
        short h = f2bf(v);
        dh[(size_t)row * ldd + c] = h;
        dl[(size_t)row * ldd + c] = f2bf(v - bf2f(h));
    }
}

// Transposed split with half-pack: logical out-row orow -> buffer row
// (orow/HR)*PSTR + (orow%HR + rowoff), ld = outld.
__global__ void transpose_split(const float* __restrict__ in,
                                short* __restrict__ outh, short* __restrict__ outl,
                                int R, int C, int HR, long PSTR, int rowoff, int outld) {
    __shared__ float tile[32][33];
    int c0 = blockIdx.x * 32, r0 = blockIdx.y * 32;
    int tx = threadIdx.x & 31, ty = threadIdx.x >> 5;
    for (int rr = ty; rr < 32; rr += 8)
        tile[rr][tx] = in[(size_t)(r0 + rr) * C + c0 + tx];
    __syncthreads();
    for (int rr = ty; rr < 32; rr += 8) {
        float v = tile[tx][rr];
        int orow = c0 + rr;
        size_t o = (size_t)(orow / HR) * PSTR + (size_t)((orow % HR) + rowoff) * outld + (r0 + tx);
        short h = f2bf(v);
        outh[o] = h;
        outl[o] = f2bf(v - bf2f(h));
    }
}

__global__ void pack_bias2(const float* __restrict__ qb, const float* __restrict__ kb,
                           float* __restrict__ dst, int D) {
    int i = blockIdx.x * 256 + threadIdx.x;
    if (i < D) {
        int p = i / (D / 2), r = i % (D / 2);
        dst[(size_t)p * D + r] = qb[i];
        dst[(size_t)p * D + D / 2 + r] = kb[i];
    }
}

// Split-bf16 MFMA GEMM on pre-split inputs: acc = AhBh + AhBl + AlBh (fp32-class).
// A [M,K] lda, B [N,K] ldb (k-contiguous). 128x128 tile; N multiple of 128.
// swap: m-tile on blockIdx.x (fast index) for tall-skinny A-locality.
// skipmode 1: early-exit if padArr[m0] (global rows). 2: batched — exit if
// padArr[zr*256+m0] or padArr[zr*256+n0] (pad is a per-batch suffix, so a
// 128-tile is all-pad iff its first row is pad).
// z: zq=z/zdiv, zr=z%zdiv; offA=zq*sA1+zr*sA2, offB=zq*sB1+zr*sB2,
// offC=zq*sC1+zr*sC2, CT offset zr*sCT, denom zr*sD.
// mode 0: o = alpha*acc + bias[ng]; optional writes C fp32 / (Ch,Cl) split / CT split
//         (layout [m/256][n][m%256]).
// mode 1: o = relu((acc+bias[ng])/denom[mg]) + (CTh+CTl)[..] + bias[ng].
__global__ __launch_bounds__(256) void mgemm(
    const short* __restrict__ Ah, const short* __restrict__ Al,
    const short* __restrict__ Bh, const short* __restrict__ Bl,
    const float* __restrict__ bias,
    float* __restrict__ C, short* __restrict__ Ch, short* __restrict__ Cl,
    short* __restrict__ CTh, short* __restrict__ CTl,
    const float* __restrict__ denom, const unsigned char* __restrict__ padArr,
    int K, int lda, int ldb, int ldc, int coloff, int zdiv,
    long sA1, long sA2, long sB1, long sB2, long sC1, long sC2,
    long sCT, long sD, float alpha, int mode, int skipmode, int swap) {
    int z = blockIdx.z, zq = z / zdiv, zr = z % zdiv;
    int m0, n0;
    if (swap) { m0 = blockIdx.x * 128; n0 = blockIdx.y * 128; }
    else      { m0 = blockIdx.y * 128; n0 = blockIdx.x * 128; }
    if (skipmode == 1 && padArr[m0]) return;
    if (skipmode == 2 && (padArr[zr * 256 + m0] || padArr[zr * 256 + n0])) return;
    const short* Ahb = Ah + (size_t)zq * sA1 + (size_t)zr * sA2;
    const short* Alb = Al + (size_t)zq * sA1 + (size_t)zr * sA2;
    const short* Bhb = Bh + (size_t)zq * sB1 + (size_t)zr * sB2;
    const short* Blb = Bl + (size_t)zq * sB1 + (size_t)zr * sB2;
    size_t offC = (size_t)zq * sC1 + (size_t)zr * sC2;
    __shared__ short lds[16384];  // Ah[0:4096] Al[4096:] Bh[8192:] Bl[12288:]
    int t = threadIdx.x;
    int lane = t & 63, w = t >> 6;
    int wm = w >> 1, wn = w & 1;
    f32x4 acc[4][4];
#pragma unroll
    for (int i = 0; i < 4; ++i)
#pragma unroll
        for (int j = 0; j < 4; ++j)
            acc[i][j] = (f32x4){0.f, 0.f, 0.f, 0.f};

    for (int k0 = 0; k0 < K; k0 += 32) {
        __syncthreads();
#pragma unroll
        for (int p = 0; p < 2; ++p) {
            int s = t + p * 256;
            int mi = (s >> 6) * 16 + (s & 15);
            int koff = k0 + ((s >> 4) & 3) * 8;
            size_t oa = (size_t)(m0 + mi) * lda + koff;
            size_t ob = (size_t)(n0 + mi) * ldb + koff;
            gl2l(Ahb + oa, &lds[s * 8]);
            gl2l(Alb + oa, &lds[4096 + s * 8]);
            gl2l(Bhb + ob, &lds[8192 + s * 8]);
            gl2l(Blb + ob, &lds[12288 + s * 8]);
        }
        __syncthreads();
        s16x8 ah[4], al4[4], bh[4], bl4[4];
#pragma unroll
        for (int i = 0; i < 4; ++i) {
            int off = ((wm * 4 + i) * 64 + lane) * 8;
            ah[i] = *(const s16x8*)&lds[off];
            al4[i] = *(const s16x8*)&lds[4096 + off];
        }
#pragma unroll
        for (int j = 0; j < 4; ++j) {
            int off = ((wn * 4 + j) * 64 + lane) * 8;
            bh[j] = *(const s16x8*)&lds[8192 + off];
            bl4[j] = *(const s16x8*)&lds[12288 + off];
        }
#pragma unroll
        for (int i = 0; i < 4; ++i)
#pragma unroll
            for (int j = 0; j < 4; ++j) {
                acc[i][j] = __builtin_amdgcn_mfma_f32_16x16x32_bf16(ah[i], bh[j], acc[i][j], 0, 0, 0);
                acc[i][j] = __builtin_amdgcn_mfma_f32_16x16x32_bf16(ah[i], bl4[j], acc[i][j], 0, 0, 0);
                acc[i][j] = __builtin_amdgcn_mfma_f32_16x16x32_bf16(al4[i], bh[j], acc[i][j], 0, 0, 0);
            }
    }

    int col = lane & 15, quad = lane >> 4;
#pragma unroll
    for (int i = 0; i < 4; ++i)
#pragma unroll
        for (int j = 0; j < 4; ++j) {
            int mg = m0 + wm * 64 + i * 16 + quad * 4;
            int ng = n0 + wn * 64 + j * 16 + col;
            f32x4 v = acc[i][j];
            if (mode == 0) {
                float bz = bias ? bias[ng] : 0.f;
                float o[4];
#pragma unroll
                for (int r = 0; r < 4; ++r) o[r] = v[r] * alpha + bz;
                if (C) {
                    float* Cb = C + offC;
#pragma unroll
                    for (int r = 0; r < 4; ++r)
                        Cb[(size_t)(mg + r) * ldc + coloff + ng] = o[r];
                }
                if (Ch) {
                    short* Chb = Ch + offC;
                    short* Clb = Cl + offC;
#pragma unroll
                    for (int r = 0; r < 4; ++r) {
                        short hh = f2bf(o[r]);
                        Chb[(size_t)(mg + r) * ldc + coloff + ng] = hh;
                        Clb[(size_t)(mg + r) * ldc + coloff + ng] = f2bf(o[r] - bf2f(hh));
                    }
                }
                if (CTh) {
                    size_t cb = (size_t)zr * sCT + (size_t)(mg >> 8) * 65536 + (size_t)ng * 256 + (mg & 255);
                    s16x4 hv, lv;
#pragma unroll
                    for (int r = 0; r < 4; ++r) {
                        short hh = f2bf(o[r]);
                        hv[r] = hh;
                        lv[r] = f2bf(o[r] - bf2f(hh));
                    }
                    *(s16x4*)&CTh[cb] = hv;
                    *(s16x4*)&CTl[cb] = lv;
                }
            } else {
                float bz = bias[ng];
                size_t cb = (size_t)zr * sCT + (size_t)(mg >> 8) * 65536 + (size_t)ng * 256 + (mg & 255);
                s16x4 th = *(const s16x4*)&CTh[cb];
                s16x4 tl = *(const s16x4*)&CTl[cb];
                const float* Db = denom + (size_t)zr * sD;
#pragma unroll
                for (int r = 0; r < 4; ++r) {
                    float sk = bf2f(th[r]) + bf2f(tl[r]);
                    float u = (v[r] + bz) / Db[mg + r];
                    float o = fmaxf(u, 0.f) + sk + bz;
                    if (C) {
                        C[offC + (size_t)(mg + r) * ldc + coloff + ng] = o;
                    } else {
                        short hh = f2bf(o);
                        Ch[offC + (size_t)(mg + r) * ldc + coloff + ng] = hh;
                        Cl[offC + (size_t)(mg + r) * ldc + coloff + ng] = f2bf(o - bf2f(hh));
                    }
                }
            }
        }
}

// Wide-N split-bf16 GEMM for the QK projections: block tile 128x256, 4 waves,
// wave tile 128x64 (R2-proven geometry, 113.9us @ D=1024; best of 7 variants
// tested R2-R12 — in-wave pipelines, B-direct, small-tile TLP, and merged-p
// block TLP all neutral or worse). A [M,K] lda, B [N,K] ldb. Writes split
// Ch/Cl = acc + bias. Skip if pad[m0].
__global__ __launch_bounds__(256, 2) void qkgemm(
    const short* __restrict__ Ah, const short* __restrict__ Al,
    const short* __restrict__ Bh, const short* __restrict__ Bl,
    const float* __restrict__ bias,
    short* __restrict__ Ch, short* __restrict__ Cl,
    const unsigned char* __restrict__ padArr,
    int K, int lda, int ldb, int ldc) {
    int m0 = blockIdx.x * 128, n0 = blockIdx.y * 256;
    if (padArr[m0]) return;
    __shared__ short lds[24576];  // Ah[0:4096] Al[4096:8192] Bh[8192:16384] Bl[16384:24576]
    int t = threadIdx.x;
    int lane = t & 63, w = t >> 6;
    f32x4 acc[8][4];
#pragma unroll
    for (int i = 0; i < 8; ++i)
#pragma unroll
        for (int j = 0; j < 4; ++j)
            acc[i][j] = (f32x4){0.f, 0.f, 0.f, 0.f};

    for (int k0 = 0; k0 < K; k0 += 32) {
        __syncthreads();
#pragma unroll
        for (int p = 0; p < 2; ++p) {  // A: 128 rows x 32 k, frag-order
            int s = t + p * 256;
            int mi = (s >> 6) * 16 + (s & 15);
            int koff = k0 + ((s >> 4) & 3) * 8;
            size_t oa = (size_t)(m0 + mi) * lda + koff;
            gl2l(Ah + oa, &lds[s * 8]);
            gl2l(Al + oa, &lds[4096 + s * 8]);
        }
#pragma unroll
        for (int p = 0; p < 4; ++p) {  // B: 256 rows x 32 k, frag-order
            int s = t + p * 256;
            int ni = (s >> 6) * 16 + (s & 15);
            int koff = k0 + ((s >> 4) & 3) * 8;
            size_t ob = (size_t)(n0 + ni) * ldb + koff;
            gl2l(Bh + ob, &lds[8192 + s * 8]);
            gl2l(Bl + ob, &lds[16384 + s * 8]);
        }
        __syncthreads();
        s16x8 bh[4], bl4[4];
#pragma unroll
        for (int j = 0; j < 4; ++j) {
            int off = ((w * 4 + j) * 64 + lane) * 8;
            bh[j] = *(const s16x8*)&lds[8192 + off];
            bl4[j] = *(const s16x8*)&lds[16384 + off];
        }
#pragma unroll
        for (int i = 0; i < 8; ++i) {
            int off = (i * 64 + lane) * 8;
            s16x8 ah = *(const s16x8*)&lds[off];
            s16x8 al4 = *(const s16x8*)&lds[4096 + off];
#pragma unroll
            for (int j = 0; j < 4; ++j) {
                acc[i][j] = __builtin_amdgcn_mfma_f32_16x16x32_bf16(ah, bh[j], acc[i][j], 0, 0, 0);
                acc[i][j] = __builtin_amdgcn_mfma_f32_16x16x32_bf16(ah, bl4[j], acc[i][j], 0, 0, 0);
                acc[i][j] = __builtin_amdgcn_mfma_f32_16x16x32_bf16(al4, bh[j], acc[i][j], 0, 0, 0);
            }
        }
    }

    int col = lane & 15, quad = lane >> 4;
#pragma unroll
    for (int i = 0; i < 8; ++i)
#pragma unroll
        for (int j = 0; j < 4; ++j) {
            int mg = m0 + i * 16 + quad * 4;
            int ng = n0 + w * 64 + j * 16 + col;
            float bz = bias[ng];
#pragma unroll
            for (int r = 0; r < 4; ++r) {
                float o = acc[i][j][r] + bz;
                short hh = f2bf(o);
                Ch[(size_t)(mg + r) * ldc + ng] = hh;
                Cl[(size_t)(mg + r) * ldc + ng] = f2bf(o - bf2f(hh));
            }
        }
}

// Masked softmax for nh heads (scores [nh][64][256][256]); accumulates into a.
// Head loop is sequential left-to-right -> accumulation order identical across
// nh groupings (bitwise-stable).
__global__ void softmax_headsum(const float* __restrict__ scores,
                                const unsigned char* __restrict__ pad,
                                float* __restrict__ a, int accum, int nh) {
    int row = blockIdx.x * 4 + (threadIdx.x >> 6);
    int lane = threadIdx.x & 63;
    int b = row >> 8;
    float* arow = a + (size_t)row * 256;
    if (pad[row]) {
        if (!accum) ((float4*)arow)[lane] = make_float4(0.f, 0.f, 0.f, 0.f);
        return;
    }
    unsigned pw = *(const unsigned*)(pad + (b << 8) + lane * 4);
    float4 racc;
    if (accum) racc = ((float4*)arow)[lane];
    else racc = make_float4(0.f, 0.f, 0.f, 0.f);
    for (int hh = 0; hh < nh; ++hh) {
        float4 s = ((const float4*)(scores + (size_t)hh * 4194304 + (size_t)row * 256))[lane];
        if (pw & 0x000000FFu) s.x = -1e9f;
        if (pw & 0x0000FF00u) s.y = -1e9f;
        if (pw & 0x00FF0000u) s.z = -1e9f;
        if (pw & 0xFF000000u) s.w = -1e9f;
        float m = fmaxf(fmaxf(s.x, s.y), fmaxf(s.z, s.w));
#pragma unroll
        for (int o = 32; o; o >>= 1) m = fmaxf(m, __shfl_xor(m, o));
        float e0 = expf(s.x - m), e1 = expf(s.y - m), e2 = expf(s.z - m), e3 = expf(s.w - m);
        float sum = e0 + e1 + e2 + e3;
#pragma unroll
        for (int o = 32; o; o >>= 1) sum += __shfl_xor(sum, o);
        float inv = 1.f / sum;
        racc.x += e0 * inv; racc.y += e1 * inv; racc.z += e2 * inv; racc.w += e3 * inv;
    }
    ((float4*)arow)[lane] = racc;
}

// ---- parallel exact top-200 radix select
__global__ void tk_init(unsigned* ghist, unsigned* prefix, int* krem, int* done) {
    int i = blockIdx.x * 256 + threadIdx.x;
    ghist[i] = 0;
    if (i < 64) { prefix[i] = 0; krem[i] = 200; done[i] = 0; }
}

// Fused hist+pick (last-block-done pattern): each of 16 slice-blocks per batch
// accumulates its LDS histogram into ghist via device-scope atomics, fences,
// and bumps done[b]; the 16th block re-reads ghist with atomic loads (coherent
// across XCDs), performs the pick inline, zeroes ghist for the next pass, and
// resets done[b]. No spin-waits, no co-residency assumption (early blocks
// exit). Replaces the separate tk_pick launch (4 launches saved per layer).
__global__ void tk_histpick(const float* __restrict__ a,
                            unsigned* __restrict__ ghist,
                            unsigned* __restrict__ prefix, int* __restrict__ krem,
                            int* __restrict__ done, float* __restrict__ thr,
                            int shift, int last) {
    __shared__ unsigned h[256];
    __shared__ int amlast;
    int b = blockIdx.x >> 4, slice = blockIdx.x & 15;
    h[threadIdx.x] = 0;
    __syncthreads();
    unsigned pfx = prefix[b];
    const unsigned* ab = (const unsigned*)(a + (size_t)b * 65536) + slice * 4096;
    for (int i = threadIdx.x; i < 4096; i += 256) {
        unsigned u = ab[i];
        if ((shift == 24) || ((u >> (shift + 8)) == pfx)) atomicAdd(&h[(u >> shift) & 255], 1u);
    }
    __syncthreads();
    if (h[threadIdx.x]) atomicAdd(&ghist[b * 256 + threadIdx.x], h[threadIdx.x]);
    __threadfence();
    if (!threadIdx.x) amlast = (atomicAdd(&done[b], 1) == 15) ? 1 : 0;
    __syncthreads();
    if (!amlast) return;
    // last block for batch b: coherent read of the full histogram + zero it
    h[threadIdx.x] = atomicAdd(&ghist[b * 256 + threadIdx.x], 0u);
    atomicExch(&ghist[b * 256 + threadIdx.x], 0u);
    __syncthreads();
    if (!threadIdx.x) {
        done[b] = 0;  // next-pass reuse; visible at kernel boundary
        int k = krem[b];
        unsigned c = 0;
        int bin = 255;
        for (; bin >= 0; --bin) { c += h[bin]; if ((int)c >= k) break; }
        if (bin < 0) bin = 0;
        krem[b] = k - (int)(c - h[bin]);
        unsigned p = (pfx << 8) | (unsigned)bin;
        prefix[b] = p;
        if (last) thr[b] = __uint_as_float(p);
    }
}

// a2(split) = a * (sel + sel^T off-diag, 1 on diag); denom = rowsum+1
__global__ void select_apply(const float* __restrict__ a, const float* __restrict__ thr,
                             short* __restrict__ a2h, short* __restrict__ a2l,
                             float* __restrict__ denom) {
    __shared__ float sb[4];
    int row = blockIdx.x;
    int b = row >> 8, i = row & 255, j = threadIdx.x;
    const float* ab = a + (size_t)b * 65536;
    float tb = thr[b];
    float v = ab[i * 256 + j];
    float vt = ab[j * 256 + i];
    float sel = (v >= tb ? 1.f : 0.f) + (vt >= tb ? 1.f : 0.f);
    if (i == j) sel = 1.f;
    float av = v * sel;
    short hh = f2bf(av);
    a2h[(size_t)row * 256 + j] = hh;
    a2l[(size_t)row * 256 + j] = f2bf(av - bf2f(hh));
    float r = blk_sum(av, sb);
    if (!j) denom[row] = r + 1.f;
}

extern "C" void kernel_launch(void* const* d_in, const int* in_sizes, int n_in,
                              void* d_out, int out_size, void* d_ws, size_t ws_size,
                              hipStream_t stream) {
    const float* adj = (const float*)d_in[0];
    const float* x0 = (const float*)d_in[1];
    const void* mask = d_in[2];
    const float* Wls[3] = {(const float*)d_in[3], (const float*)d_in[5], (const float*)d_in[7]};
    const float* bls[3] = {(const float*)d_in[4], (const float*)d_in[6], (const float*)d_in[8]};
    const float* qws[2] = {(const float*)d_in[9], (const float*)d_in[13]};
    const float* qbs[2] = {(const float*)d_in[10], (const float*)d_in[14]};
    const float* kws[2] = {(const float*)d_in[11], (const float*)d_in[15]};
    const float* kbs[2] = {(const float*)d_in[12], (const float*)d_in[16]};

    char* base = (char*)d_ws;
    size_t cur = 0;
    auto alloc = [&](size_t bytes) -> void* {
        cur = (cur + 1023) & ~(size_t)1023;
        void* p = base + cur;
        cur += bytes;
        return p;
    };
    const size_t NROW = 16384;
    int* flags = (int*)alloc(12);
    unsigned char* pad = (unsigned char*)alloc(NROW);
    float* denom = (float*)alloc(NROW * 4);
    float* thr = (float*)alloc(256);
    unsigned* prefix = (unsigned*)alloc(256);
    int* krem = (int*)alloc(256);
    int* done = (int*)alloc(256);
    unsigned* ghist = (unsigned*)alloc(64 * 256 * 4);
    short* WTh = (short*)alloc((size_t)2304 * 256 * 2);
    short* WTl = (short*)alloc((size_t)2304 * 256 * 2);
    short* qkwPh = (short*)alloc((size_t)2 * 1024 * 1024 * 2);  // [half p][D rows][D]
    short* qkwPl = (short*)alloc((size_t)2 * 1024 * 1024 * 2);
    float* qkb = (float*)alloc((size_t)2 * 1024 * 4);
    short* xh = (short*)alloc(NROW * 1024 * 2);
    short* xl = (short*)alloc(NROW * 1024 * 2);
    float* a = (float*)alloc(NROW * 256 * 4);
    short* a2h = (short*)alloc(NROW * 256 * 2);
    short* a2l = (short*)alloc(NROW * 256 * 2);
    short* QKh = (short*)alloc(NROW * 1024 * 2);  // half-heads Q|K [16384, D]
    short* QKl = (short*)alloc(NROW * 1024 * 2);
    // Sreg: tzT split (16.8 MB) | scores alias (disjoint lifetime).
    // Attempt 4-head scores (64 MB) -> merged z=256 scores dispatch per p
    // (R11-verified: 1226.6us). Fallback: 2-head scores -> exact R9 sequence.
    size_t cur_save = cur;
    char* Sreg = (char*)alloc((size_t)4 * 64 * 65536 * 4);
    int sc4 = 1;
    if (ws_size < cur) {
        cur = cur_save;
        Sreg = (char*)alloc((size_t)2 * 64 * 65536 * 4);
        sc4 = 0;
        if (ws_size < cur) return;  // clean failure instead of device fault
    }

    short* tzTh = (short*)Sreg;
    short* tzTl = (short*)Sreg + (size_t)64 * 65536;
    float* scores = (float*)Sreg;  // [nh][64][256][256] fp32, alias over tzT
    short* adjh = QKh;             // adj split dead once attention 0 starts
    short* adjl = QKl;
    const int Ks[3] = {512, 768, 1024};
    const long offW[3] = {0, (long)512 * 256, (long)(512 + 768) * 256};

    init_flags<<<1, 64, 0, stream>>>(flags);
    detect_mask<<<64, 256, 0, stream>>>((const unsigned int*)mask, 1048576, flags);
    extract_pad<<<64, 256, 0, stream>>>(mask, flags, pad);
    rowsum_plus1<<<16384, 256, 0, stream>>>(adj, denom);
    split_mat<<<16384, 256, 0, stream>>>(x0, 512, 512, xh, xl, 1024);
    split_mat<<<16384, 256, 0, stream>>>(adj, 256, 256, adjh, adjl, 256);
    for (int l = 0; l < 3; ++l)
        transpose_split<<<dim3(8, Ks[l] / 32), 256, 0, stream>>>(
            Wls[l], WTh + offW[l], WTl + offW[l], Ks[l], 256, 256, 0, 0, Ks[l]);

    for (int l = 0; l < 3; ++l) {
        int Kl = Ks[l];
        // tzT(split) = (x @ Wl)^T per batch  (CT-only write), swap grid for A-locality
        mgemm<<<dim3(128, 2, 1), 256, 0, stream>>>(
            xh, xl, WTh + offW[l], WTl + offW[l], nullptr,
            nullptr, nullptr, nullptr, tzTh, tzTl, nullptr, nullptr,
            Kl, 1024, Kl, 0, 0, 1,
            0, 0, 0, 0, 0, 0, 0, 0, 1.f, 0, 0, 1);
        // fused GCN: out = relu((A@tz + b)/denom) + tz + b
        const short* Aah = (l == 0) ? adjh : a2h;
        const short* Aal = (l == 0) ? adjl : a2l;
        if (l < 2) {
            mgemm<<<dim3(2, 2, 64), 256, 0, stream>>>(
                Aah, Aal, tzTh, tzTl, bls[l],
                nullptr, xh, xl, tzTh, tzTl, denom, nullptr,
                256, 256, 256, 1024, Kl, 64,
                0, 65536, 0, 65536, 0, (long)256 * 1024, 65536, 256, 1.f, 1, 0, 0);
        } else {
            mgemm<<<dim3(2, 2, 64), 256, 0, stream>>>(
                Aah, Aal, tzTh, tzTl, bls[l],
                (float*)d_out, nullptr, nullptr, tzTh, tzTl, denom, nullptr,
                256, 256, 256, 256, 0, 64,
                0, 65536, 0, 65536, 0, 65536, 65536, 256, 1.f, 1, 0, 0);
            break;
        }

        // ---- attention l (D = Ks[l+1], dk = D/8), two head-halves of 4 heads
        int D = Ks[l + 1], dk = D / 8, HD = D / 2;
        float scale = 1.f / sqrtf((float)dk);
        // packed weights: [p][0:HD]=Wq^T half p, [p][HD:D]=Wk^T half p
        transpose_split<<<dim3(D / 32, D / 32), 256, 0, stream>>>(
            qws[l], qkwPh, qkwPl, D, D, HD, (long)D * D, 0, D);
        transpose_split<<<dim3(D / 32, D / 32), 256, 0, stream>>>(
            kws[l], qkwPh, qkwPl, D, D, HD, (long)D * D, HD, D);
        pack_bias2<<<4, 256, 0, stream>>>(qbs[l], kbs[l], qkb, D);

        for (int p = 0; p < 2; ++p) {
            // QK[:,0:HD]=Q(4 heads), QK[:,HD:D]=K(4 heads): one dispatch, N=D.
            qkgemm<<<dim3(128, D / 256), 256, 0, stream>>>(
                xh, xl, qkwPh + (size_t)p * D * D, qkwPl + (size_t)p * D * D,
                qkb + (size_t)p * D, QKh, QKl, pad, D, 1024, D, D);
            if (sc4) {
                // ALL 4 heads of half p in ONE dispatch (zq=head via sA1=dk):
                // 1024 blocks in flight vs 2x512 sequential.
                mgemm<<<dim3(2, 2, 256), 256, 0, stream>>>(
                    QKh, QKl, QKh + HD, QKl + HD,
                    nullptr, scores, nullptr, nullptr, nullptr, nullptr, nullptr, pad,
                    dk, D, D, 256, 0, 64,
                    dk, (long)256 * D, dk, (long)256 * D, (long)64 * 65536, 65536,
                    0, 0, scale, 0, 2, 0);
                softmax_headsum<<<4096, 256, 0, stream>>>(scores, pad, a, p ? 1 : 0, 4);
            } else {
                for (int hp = 0; hp < 2; ++hp) {  // 2 heads per scores dispatch
                    mgemm<<<dim3(2, 2, 128), 256, 0, stream>>>(
                        QKh + (size_t)(hp * 2) * dk, QKl + (size_t)(hp * 2) * dk,
                        QKh + HD + (size_t)(hp * 2) * dk, QKl + HD + (size_t)(hp * 2) * dk,
                        nullptr, scores, nullptr, nullptr, nullptr, nullptr, nullptr, pad,
                        dk, D, D, 256, 0, 64,
                        dk, (long)256 * D, dk, (long)256 * D, (long)64 * 65536, 65536,
                        0, 0, scale, 0, 2, 0);
                    softmax_headsum<<<4096, 256, 0, stream>>>(scores, pad, a, (p * 2 + hp) ? 1 : 0, 2);
                }
            }
        }
        tk_init<<<64, 256, 0, stream>>>(ghist, prefix, krem, done);
        for (int pp = 0; pp < 4; ++pp)
            tk_histpick<<<1024, 256, 0, stream>>>(a, ghist, prefix, krem, done, thr,
                                                  24 - 8 * pp, pp == 3);
        select_apply<<<16384, 256, 0, stream>>>(a, thr, a2h, a2l, denom);
    }
}

// Round 15
// 1225.923 us; speedup vs baseline: 1.3644x; 1.3644x over previous
//
#include <hip/hip_runtime.h>
#include <math.h>

// B=64, S=256, IN_DIM=512, MEM=256, LAYERS=3, HEADS=8, TOP_K=200. NROW=16384.

typedef __attribute__((ext_vector_type(8))) short s16x8;
typedef __attribute__((ext_vector_type(4))) short s16x4;
typedef __attribute__((ext_vector_type(4))) float f32x4;

__device__ __forceinline__ short f2bf(float x) {
    unsigned u = __float_as_uint(x);
    u += 0x7FFF + ((u >> 16) & 1);  // rn-even
    return (short)(u >> 16);
}
__device__ __forceinline__ float bf2f(short h) {
    return __uint_as_float(((unsigned)(unsigned short)h) << 16);
}

// async global->LDS, 16B per lane. LDS layout must be lane-contiguous (ours is).
__device__ __forceinline__ void gl2l(const void* g, void* l) {
    __builtin_amdgcn_global_load_lds(
        (const __attribute__((address_space(1))) unsigned int*)g,
        (__attribute__((address_space(3))) unsigned int*)l, 16, 0, 0);
}

__device__ __forceinline__ float blk_sum(float v, float* sb) {
#pragma unroll
    for (int o = 32; o; o >>= 1) v += __shfl_down(v, o);
    int lane = threadIdx.x & 63, w = threadIdx.x >> 6;
    if (!lane) sb[w] = v;
    __syncthreads();
    float r = sb[0] + sb[1] + sb[2] + sb[3];
    __syncthreads();
    return r;
}

__global__ void init_flags(int* flags) {
    if (threadIdx.x < 3) flags[threadIdx.x] = 0;
}

__global__ void detect_mask(const unsigned int* __restrict__ w, int nwords, int* flags) {
    int stride = gridDim.x * blockDim.x;
    int l_u8 = 0, l_f32 = 0, l_nz = 0;
    for (int i = blockIdx.x * blockDim.x + threadIdx.x; i < nwords; i += stride) {
        unsigned v = w[i];
        if (v) {
            l_nz = 1;
            if (v == 0x3F800000u) l_f32 = 1;
            else if (v > 1u) l_u8 = 1;
        }
    }
    if (__ballot(l_u8) && (threadIdx.x & 63) == 0) atomicOr(&flags[0], 1);
    if (__ballot(l_f32) && (threadIdx.x & 63) == 0) atomicOr(&flags[1], 1);
    if (__ballot(l_nz) && (threadIdx.x & 63) == 0) atomicOr(&flags[2], 1);
}

__global__ void extract_pad(const void* __restrict__ mask, const int* __restrict__ flags,
                            unsigned char* __restrict__ pad) {
    int b = blockIdx.x, i = threadIdx.x;
    int v;
    size_t idx = (size_t)b * 65536 + (size_t)i * 256;
    if (flags[0]) v = ((const unsigned char*)mask)[idx] != 0;
    else if (flags[2]) v = ((const unsigned int*)mask)[idx] != 0;
    else v = 0;
    pad[b * 256 + i] = (unsigned char)v;
}

__global__ void rowsum_plus1(const float* __restrict__ x, float* __restrict__ out) {
    __shared__ float sb[4];
    int row = blockIdx.x;
    float v = x[(size_t)row * 256 + threadIdx.x];
    float r = blk_sum(v, sb);
    if (!threadIdx.x) out[row] = r + 1.f;
}

__global__ void split_mat(const float* __restrict__ src, int ldsrc, int width,
                          short* __restrict__ dh, short* __restrict__ dl, int ldd) {
    int row = blockIdx.x;
    for (int c = threadIdx.x; c < width; c += 256) {
        float v = src[(size_t)row * ldsrc + c];
        short h = f2bf(v);
        dh[(size_t)row * ldd + c] = h;
        dl[(size_t)row * ldd + c] = f2bf(v - bf2f(h));
    }
}

// Transposed split with half-pack: logical out-row orow -> buffer row
// (orow/HR)*PSTR + (orow%HR + rowoff), ld = outld.
__global__ void transpose_split(const float* __restrict__ in,
                                short* __restrict__ outh, short* __restrict__ outl,
                                int R, int C, int HR, long PSTR, int rowoff, int outld) {
    __shared__ float tile[32][33];
    int c0 = blockIdx.x * 32, r0 = blockIdx.y * 32;
    int tx = threadIdx.x & 31, ty = threadIdx.x >> 5;
    for (int rr = ty; rr < 32; rr += 8)
        tile[rr][tx] = in[(size_t)(r0 + rr) * C + c0 + tx];
    __syncthreads();
    for (int rr = ty; rr < 32; rr += 8) {
        float v = tile[tx][rr];
        int orow = c0 + rr;
        size_t o = (size_t)(orow / HR) * PSTR + (size_t)((orow % HR) + rowoff) * outld + (r0 + tx);
        short h = f2bf(v);
        outh[o] = h;
        outl[o] = f2bf(v - bf2f(h));
    }
}

__global__ void pack_bias2(const float* __restrict__ qb, const float* __restrict__ kb,
                           float* __restrict__ dst, int D) {
    int i = blockIdx.x * 256 + threadIdx.x;
    if (i < D) {
        int p = i / (D / 2), r = i % (D / 2);
        dst[(size_t)p * D + r] = qb[i];
        dst[(size_t)p * D + D / 2 + r] = kb[i];
    }
}

// Split-bf16 MFMA GEMM on pre-split inputs: acc = AhBh + AhBl + AlBh (fp32-class).
// A [M,K] lda, B [N,K] ldb (k-contiguous). 128x128 tile; N multiple of 128.
// swap: m-tile on blockIdx.x (fast index) for tall-skinny A-locality.
// skipmode 1: early-exit if padArr[m0] (global rows). 2: batched — exit if
// padArr[zr*256+m0] or padArr[zr*256+n0] (pad is a per-batch suffix, so a
// 128-tile is all-pad iff its first row is pad).
// z: zq=z/zdiv, zr=z%zdiv; offA=zq*sA1+zr*sA2, offB=zq*sB1+zr*sB2,
// offC=zq*sC1+zr*sC2, CT offset zr*sCT, denom zr*sD.
// mode 0: o = alpha*acc + bias[ng]; optional writes C fp32 / (Ch,Cl) split / CT split
//         (layout [m/256][n][m%256]).
// mode 1: o = relu((acc+bias[ng])/denom[mg]) + (CTh+CTl)[..] + bias[ng].
__global__ __launch_bounds__(256) void mgemm(
    const short* __restrict__ Ah, const short* __restrict__ Al,
    const short* __restrict__ Bh, const short* __restrict__ Bl,
    const float* __restrict__ bias,
    float* __restrict__ C, short* __restrict__ Ch, short* __restrict__ Cl,
    short* __restrict__ CTh, short* __restrict__ CTl,
    const float* __restrict__ denom, const unsigned char* __restrict__ padArr,
    int K, int lda, int ldb, int ldc, int coloff, int zdiv,
    long sA1, long sA2, long sB1, long sB2, long sC1, long sC2,
    long sCT, long sD, float alpha, int mode, int skipmode, int swap) {
    int z = blockIdx.z, zq = z / zdiv, zr = z % zdiv;
    int m0, n0;
    if (swap) { m0 = blockIdx.x * 128; n0 = blockIdx.y * 128; }
    else      { m0 = blockIdx.y * 128; n0 = blockIdx.x * 128; }
    if (skipmode == 1 && padArr[m0]) return;
    if (skipmode == 2 && (padArr[zr * 256 + m0] || padArr[zr * 256 + n0])) return;
    const short* Ahb = Ah + (size_t)zq * sA1 + (size_t)zr * sA2;
    const short* Alb = Al + (size_t)zq * sA1 + (size_t)zr * sA2;
    const short* Bhb = Bh + (size_t)zq * sB1 + (size_t)zr * sB2;
    const short* Blb = Bl + (size_t)zq * sB1 + (size_t)zr * sB2;
    size_t offC = (size_t)zq * sC1 + (size_t)zr * sC2;
    __shared__ short lds[16384];  // Ah[0:4096] Al[4096:] Bh[8192:] Bl[12288:]
    int t = threadIdx.x;
    int lane = t & 63, w = t >> 6;
    int wm = w >> 1, wn = w & 1;
    f32x4 acc[4][4];
#pragma unroll
    for (int i = 0; i < 4; ++i)
#pragma unroll
        for (int j = 0; j < 4; ++j)
            acc[i][j] = (f32x4){0.f, 0.f, 0.f, 0.f};

    for (int k0 = 0; k0 < K; k0 += 32) {
        __syncthreads();
#pragma unroll
        for (int p = 0; p < 2; ++p) {
            int s = t + p * 256;
            int mi = (s >> 6) * 16 + (s & 15);
            int koff = k0 + ((s >> 4) & 3) * 8;
            size_t oa = (size_t)(m0 + mi) * lda + koff;
            size_t ob = (size_t)(n0 + mi) * ldb + koff;
            gl2l(Ahb + oa, &lds[s * 8]);
            gl2l(Alb + oa, &lds[4096 + s * 8]);
            gl2l(Bhb + ob, &lds[8192 + s * 8]);
            gl2l(Blb + ob, &lds[12288 + s * 8]);
        }
        __syncthreads();
        s16x8 ah[4], al4[4], bh[4], bl4[4];
#pragma unroll
        for (int i = 0; i < 4; ++i) {
            int off = ((wm * 4 + i) * 64 + lane) * 8;
            ah[i] = *(const s16x8*)&lds[off];
            al4[i] = *(const s16x8*)&lds[4096 + off];
        }
#pragma unroll
        for (int j = 0; j < 4; ++j) {
            int off = ((wn * 4 + j) * 64 + lane) * 8;
            bh[j] = *(const s16x8*)&lds[8192 + off];
            bl4[j] = *(const s16x8*)&lds[12288 + off];
        }
#pragma unroll
        for (int i = 0; i < 4; ++i)
#pragma unroll
            for (int j = 0; j < 4; ++j) {
                acc[i][j] = __builtin_amdgcn_mfma_f32_16x16x32_bf16(ah[i], bh[j], acc[i][j], 0, 0, 0);
                acc[i][j] = __builtin_amdgcn_mfma_f32_16x16x32_bf16(ah[i], bl4[j], acc[i][j], 0, 0, 0);
                acc[i][j] = __builtin_amdgcn_mfma_f32_16x16x32_bf16(al4[i], bh[j], acc[i][j], 0, 0, 0);
            }
    }

    int col = lane & 15, quad = lane >> 4;
#pragma unroll
    for (int i = 0; i < 4; ++i)
#pragma unroll
        for (int j = 0; j < 4; ++j) {
            int mg = m0 + wm * 64 + i * 16 + quad * 4;
            int ng = n0 + wn * 64 + j * 16 + col;
            f32x4 v = acc[i][j];
            if (mode == 0) {
                float bz = bias ? bias[ng] : 0.f;
                float o[4];
#pragma unroll
                for (int r = 0; r < 4; ++r) o[r] = v[r] * alpha + bz;
                if (C) {
                    float* Cb = C + offC;
#pragma unroll
                    for (int r = 0; r < 4; ++r)
                        Cb[(size_t)(mg + r) * ldc + coloff + ng] = o[r];
                }
                if (Ch) {
                    short* Chb = Ch + offC;
                    short* Clb = Cl + offC;
#pragma unroll
                    for (int r = 0; r < 4; ++r) {
                        short hh = f2bf(o[r]);
                        Chb[(size_t)(mg + r) * ldc + coloff + ng] = hh;
                        Clb[(size_t)(mg + r) * ldc + coloff + ng] = f2bf(o[r] - bf2f(hh));
                    }
                }
                if (CTh) {
                    size_t cb = (size_t)zr * sCT + (size_t)(mg >> 8) * 65536 + (size_t)ng * 256 + (mg & 255);
                    s16x4 hv, lv;
#pragma unroll
                    for (int r = 0; r < 4; ++r) {
                        short hh = f2bf(o[r]);
                        hv[r] = hh;
                        lv[r] = f2bf(o[r] - bf2f(hh));
                    }
                    *(s16x4*)&CTh[cb] = hv;
                    *(s16x4*)&CTl[cb] = lv;
                }
            } else {
                float bz = bias[ng];
                size_t cb = (size_t)zr * sCT + (size_t)(mg >> 8) * 65536 + (size_t)ng * 256 + (mg & 255);
                s16x4 th = *(const s16x4*)&CTh[cb];
                s16x4 tl = *(const s16x4*)&CTl[cb];
                const float* Db = denom + (size_t)zr * sD;
#pragma unroll
                for (int r = 0; r < 4; ++r) {
                    float sk = bf2f(th[r]) + bf2f(tl[r]);
                    float u = (v[r] + bz) / Db[mg + r];
                    float o = fmaxf(u, 0.f) + sk + bz;
                    if (C) {
                        C[offC + (size_t)(mg + r) * ldc + coloff + ng] = o;
                    } else {
                        short hh = f2bf(o);
                        Ch[offC + (size_t)(mg + r) * ldc + coloff + ng] = hh;
                        Cl[offC + (size_t)(mg + r) * ldc + coloff + ng] = f2bf(o - bf2f(hh));
                    }
                }
            }
        }
}

// Wide-N split-bf16 GEMM for the QK projections: block tile 128x256, 4 waves,
// wave tile 128x64 (R2-proven geometry, 113.9us @ D=1024; best of 7 variants
// tested R2-R12 — in-wave pipelines, B-direct, small-tile TLP, and merged-p
// block TLP all neutral or worse). A [M,K] lda, B [N,K] ldb. Writes split
// Ch/Cl = acc + bias. Skip if pad[m0].
__global__ __launch_bounds__(256, 2) void qkgemm(
    const short* __restrict__ Ah, const short* __restrict__ Al,
    const short* __restrict__ Bh, const short* __restrict__ Bl,
    const float* __restrict__ bias,
    short* __restrict__ Ch, short* __restrict__ Cl,
    const unsigned char* __restrict__ padArr,
    int K, int lda, int ldb, int ldc) {
    int m0 = blockIdx.x * 128, n0 = blockIdx.y * 256;
    if (padArr[m0]) return;
    __shared__ short lds[24576];  // Ah[0:4096] Al[4096:8192] Bh[8192:16384] Bl[16384:24576]
    int t = threadIdx.x;
    int lane = t & 63, w = t >> 6;
    f32x4 acc[8][4];
#pragma unroll
    for (int i = 0; i < 8; ++i)
#pragma unroll
        for (int j = 0; j < 4; ++j)
            acc[i][j] = (f32x4){0.f, 0.f, 0.f, 0.f};

    for (int k0 = 0; k0 < K; k0 += 32) {
        __syncthreads();
#pragma unroll
        for (int p = 0; p < 2; ++p) {  // A: 128 rows x 32 k, frag-order
            int s = t + p * 256;
            int mi = (s >> 6) * 16 + (s & 15);
            int koff = k0 + ((s >> 4) & 3) * 8;
            size_t oa = (size_t)(m0 + mi) * lda + koff;
            gl2l(Ah + oa, &lds[s * 8]);
            gl2l(Al + oa, &lds[4096 + s * 8]);
        }
#pragma unroll
        for (int p = 0; p < 4; ++p) {  // B: 256 rows x 32 k, frag-order
            int s = t + p * 256;
            int ni = (s >> 6) * 16 + (s & 15);
            int koff = k0 + ((s >> 4) & 3) * 8;
            size_t ob = (size_t)(n0 + ni) * ldb + koff;
            gl2l(Bh + ob, &lds[8192 + s * 8]);
            gl2l(Bl + ob, &lds[16384 + s * 8]);
        }
        __syncthreads();
        s16x8 bh[4], bl4[4];
#pragma unroll
        for (int j = 0; j < 4; ++j) {
            int off = ((w * 4 + j) * 64 + lane) * 8;
            bh[j] = *(const s16x8*)&lds[8192 + off];
            bl4[j] = *(const s16x8*)&lds[16384 + off];
        }
#pragma unroll
        for (int i = 0; i < 8; ++i) {
            int off = (i * 64 + lane) * 8;
            s16x8 ah = *(const s16x8*)&lds[off];
            s16x8 al4 = *(const s16x8*)&lds[4096 + off];
#pragma unroll
            for (int j = 0; j < 4; ++j) {
                acc[i][j] = __builtin_amdgcn_mfma_f32_16x16x32_bf16(ah, bh[j], acc[i][j], 0, 0, 0);
                acc[i][j] = __builtin_amdgcn_mfma_f32_16x16x32_bf16(ah, bl4[j], acc[i][j], 0, 0, 0);
                acc[i][j] = __builtin_amdgcn_mfma_f32_16x16x32_bf16(al4, bh[j], acc[i][j], 0, 0, 0);
            }
        }
    }

    int col = lane & 15, quad = lane >> 4;
#pragma unroll
    for (int i = 0; i < 8; ++i)
#pragma unroll
        for (int j = 0; j < 4; ++j) {
            int mg = m0 + i * 16 + quad * 4;
            int ng = n0 + w * 64 + j * 16 + col;
            float bz = bias[ng];
#pragma unroll
            for (int r = 0; r < 4; ++r) {
                float o = acc[i][j][r] + bz;
                short hh = f2bf(o);
                Ch[(size_t)(mg + r) * ldc + ng] = hh;
                Cl[(size_t)(mg + r) * ldc + ng] = f2bf(o - bf2f(hh));
            }
        }
}

// Masked softmax for nh heads (scores [nh][64][256][256]); accumulates into a.
// Head loop is sequential left-to-right -> accumulation order identical across
// nh groupings (bitwise-stable).
__global__ void softmax_headsum(const float* __restrict__ scores,
                                const unsigned char* __restrict__ pad,
                                float* __restrict__ a, int accum, int nh) {
    int row = blockIdx.x * 4 + (threadIdx.x >> 6);
    int lane = threadIdx.x & 63;
    int b = row >> 8;
    float* arow = a + (size_t)row * 256;
    if (pad[row]) {
        if (!accum) ((float4*)arow)[lane] = make_float4(0.f, 0.f, 0.f, 0.f);
        return;
    }
    unsigned pw = *(const unsigned*)(pad + (b << 8) + lane * 4);
    float4 racc;
    if (accum) racc = ((float4*)arow)[lane];
    else racc = make_float4(0.f, 0.f, 0.f, 0.f);
    for (int hh = 0; hh < nh; ++hh) {
        float4 s = ((const float4*)(scores + (size_t)hh * 4194304 + (size_t)row * 256))[lane];
        if (pw & 0x000000FFu) s.x = -1e9f;
        if (pw & 0x0000FF00u) s.y = -1e9f;
        if (pw & 0x00FF0000u) s.z = -1e9f;
        if (pw & 0xFF000000u) s.w = -1e9f;
        float m = fmaxf(fmaxf(s.x, s.y), fmaxf(s.z, s.w));
#pragma unroll
        for (int o = 32; o; o >>= 1) m = fmaxf(m, __shfl_xor(m, o));
        float e0 = expf(s.x - m), e1 = expf(s.y - m), e2 = expf(s.z - m), e3 = expf(s.w - m);
        float sum = e0 + e1 + e2 + e3;
#pragma unroll
        for (int o = 32; o; o >>= 1) sum += __shfl_xor(sum, o);
        float inv = 1.f / sum;
        racc.x += e0 * inv; racc.y += e1 * inv; racc.z += e2 * inv; racc.w += e3 * inv;
    }
    ((float4*)arow)[lane] = racc;
}

// ---- parallel exact top-200 radix select
__global__ void tk_init(unsigned* ghist, unsigned* prefix, int* krem) {
    int i = blockIdx.x * 256 + threadIdx.x;
    ghist[i] = 0;
    if (i < 64) { prefix[i] = 0; krem[i] = 200; }
}

__global__ void tk_hist(const float* __restrict__ a, const unsigned* __restrict__ prefix,
                        unsigned* __restrict__ ghist, int shift) {
    __shared__ unsigned h[256];
    int b = blockIdx.x >> 4, slice = blockIdx.x & 15;
    h[threadIdx.x] = 0;
    __syncthreads();
    unsigned pfx = prefix[b];
    const unsigned* ab = (const unsigned*)(a + (size_t)b * 65536) + slice * 4096;
    for (int i = threadIdx.x; i < 4096; i += 256) {
        unsigned u = ab[i];
        if ((shift == 24) || ((u >> (shift + 8)) == pfx)) atomicAdd(&h[(u >> shift) & 255], 1u);
    }
    __syncthreads();
    if (h[threadIdx.x]) atomicAdd(&ghist[b * 256 + threadIdx.x], h[threadIdx.x]);
}

__global__ void tk_pick(unsigned* __restrict__ ghist, unsigned* __restrict__ prefix,
                        int* __restrict__ krem, float* __restrict__ thr, int last) {
    __shared__ unsigned h[256];
    int b = blockIdx.x;
    h[threadIdx.x] = ghist[b * 256 + threadIdx.x];
    ghist[b * 256 + threadIdx.x] = 0;
    __syncthreads();
    if (!threadIdx.x) {
        int k = krem[b];
        unsigned c = 0;
        int bin = 255;
        for (; bin >= 0; --bin) { c += h[bin]; if ((int)c >= k) break; }
        if (bin < 0) bin = 0;
        krem[b] = k - (int)(c - h[bin]);
        unsigned p = (prefix[b] << 8) | (unsigned)bin;
        prefix[b] = p;
        if (last) thr[b] = __uint_as_float(p);
    }
}

// a2(split) = a * (sel + sel^T off-diag, 1 on diag); denom = rowsum+1
__global__ void select_apply(const float* __restrict__ a, const float* __restrict__ thr,
                             short* __restrict__ a2h, short* __restrict__ a2l,
                             float* __restrict__ denom) {
    __shared__ float sb[4];
    int row = blockIdx.x;
    int b = row >> 8, i = row & 255, j = threadIdx.x;
    const float* ab = a + (size_t)b * 65536;
    float tb = thr[b];
    float v = ab[i * 256 + j];
    float vt = ab[j * 256 + i];
    float sel = (v >= tb ? 1.f : 0.f) + (vt >= tb ? 1.f : 0.f);
    if (i == j) sel = 1.f;
    float av = v * sel;
    short hh = f2bf(av);
    a2h[(size_t)row * 256 + j] = hh;
    a2l[(size_t)row * 256 + j] = f2bf(av - bf2f(hh));
    float r = blk_sum(av, sb);
    if (!j) denom[row] = r + 1.f;
}

extern "C" void kernel_launch(void* const* d_in, const int* in_sizes, int n_in,
                              void* d_out, int out_size, void* d_ws, size_t ws_size,
                              hipStream_t stream) {
    const float* adj = (const float*)d_in[0];
    const float* x0 = (const float*)d_in[1];
    const void* mask = d_in[2];
    const float* Wls[3] = {(const float*)d_in[3], (const float*)d_in[5], (const float*)d_in[7]};
    const float* bls[3] = {(const float*)d_in[4], (const float*)d_in[6], (const float*)d_in[8]};
    const float* qws[2] = {(const float*)d_in[9], (const float*)d_in[13]};
    const float* qbs[2] = {(const float*)d_in[10], (const float*)d_in[14]};
    const float* kws[2] = {(const float*)d_in[11], (const float*)d_in[15]};
    const float* kbs[2] = {(const float*)d_in[12], (const float*)d_in[16]};

    char* base = (char*)d_ws;
    size_t cur = 0;
    auto alloc = [&](size_t bytes) -> void* {
        cur = (cur + 1023) & ~(size_t)1023;
        void* p = base + cur;
        cur += bytes;
        return p;
    };
    const size_t NROW = 16384;
    int* flags = (int*)alloc(12);
    unsigned char* pad = (unsigned char*)alloc(NROW);
    float* denom = (float*)alloc(NROW * 4);
    float* thr = (float*)alloc(256);
    unsigned* prefix = (unsigned*)alloc(256);
    int* krem = (int*)alloc(256);
    unsigned* ghist = (unsigned*)alloc(64 * 256 * 4);
    short* WTh = (short*)alloc((size_t)2304 * 256 * 2);
    short* WTl = (short*)alloc((size_t)2304 * 256 * 2);
    short* qkwPh = (short*)alloc((size_t)2 * 1024 * 1024 * 2);  // [half p][D rows][D]
    short* qkwPl = (short*)alloc((size_t)2 * 1024 * 1024 * 2);
    float* qkb = (float*)alloc((size_t)2 * 1024 * 4);
    short* xh = (short*)alloc(NROW * 1024 * 2);
    short* xl = (short*)alloc(NROW * 1024 * 2);
    float* a = (float*)alloc(NROW * 256 * 4);
    short* a2h = (short*)alloc(NROW * 256 * 2);
    short* a2l = (short*)alloc(NROW * 256 * 2);
    short* QKh = (short*)alloc(NROW * 1024 * 2);  // half-heads Q|K [16384, D]
    short* QKl = (short*)alloc(NROW * 1024 * 2);
    // Sreg: tzT split (16.8 MB) | scores alias (disjoint lifetime).
    // Attempt 4-head scores (64 MB) -> merged z=256 scores dispatch per p
    // (R11-verified: 1226.6us). Fallback: 2-head scores -> exact R9 sequence.
    size_t cur_save = cur;
    char* Sreg = (char*)alloc((size_t)4 * 64 * 65536 * 4);
    int sc4 = 1;
    if (ws_size < cur) {
        cur = cur_save;
        Sreg = (char*)alloc((size_t)2 * 64 * 65536 * 4);
        sc4 = 0;
        if (ws_size < cur) return;  // clean failure instead of device fault
    }

    short* tzTh = (short*)Sreg;
    short* tzTl = (short*)Sreg + (size_t)64 * 65536;
    float* scores = (float*)Sreg;  // [nh][64][256][256] fp32, alias over tzT
    short* adjh = QKh;             // adj split dead once attention 0 starts
    short* adjl = QKl;
    const int Ks[3] = {512, 768, 1024};
    const long offW[3] = {0, (long)512 * 256, (long)(512 + 768) * 256};

    init_flags<<<1, 64, 0, stream>>>(flags);
    detect_mask<<<64, 256, 0, stream>>>((const unsigned int*)mask, 1048576, flags);
    extract_pad<<<64, 256, 0, stream>>>(mask, flags, pad);
    rowsum_plus1<<<16384, 256, 0, stream>>>(adj, denom);
    split_mat<<<16384, 256, 0, stream>>>(x0, 512, 512, xh, xl, 1024);
    split_mat<<<16384, 256, 0, stream>>>(adj, 256, 256, adjh, adjl, 256);
    for (int l = 0; l < 3; ++l)
        transpose_split<<<dim3(8, Ks[l] / 32), 256, 0, stream>>>(
            Wls[l], WTh + offW[l], WTl + offW[l], Ks[l], 256, 256, 0, 0, Ks[l]);

    for (int l = 0; l < 3; ++l) {
        int Kl = Ks[l];
        // tzT(split) = (x @ Wl)^T per batch  (CT-only write), swap grid for A-locality
        mgemm<<<dim3(128, 2, 1), 256, 0, stream>>>(
            xh, xl, WTh + offW[l], WTl + offW[l], nullptr,
            nullptr, nullptr, nullptr, tzTh, tzTl, nullptr, nullptr,
            Kl, 1024, Kl, 0, 0, 1,
            0, 0, 0, 0, 0, 0, 0, 0, 1.f, 0, 0, 1);
        // fused GCN: out = relu((A@tz + b)/denom) + tz + b
        const short* Aah = (l == 0) ? adjh : a2h;
        const short* Aal = (l == 0) ? adjl : a2l;
        if (l < 2) {
            mgemm<<<dim3(2, 2, 64), 256, 0, stream>>>(
                Aah, Aal, tzTh, tzTl, bls[l],
                nullptr, xh, xl, tzTh, tzTl, denom, nullptr,
                256, 256, 256, 1024, Kl, 64,
                0, 65536, 0, 65536, 0, (long)256 * 1024, 65536, 256, 1.f, 1, 0, 0);
        } else {
            mgemm<<<dim3(2, 2, 64), 256, 0, stream>>>(
                Aah, Aal, tzTh, tzTl, bls[l],
                (float*)d_out, nullptr, nullptr, tzTh, tzTl, denom, nullptr,
                256, 256, 256, 256, 0, 64,
                0, 65536, 0, 65536, 0, 65536, 65536, 256, 1.f, 1, 0, 0);
            break;
        }

        // ---- attention l (D = Ks[l+1], dk = D/8), two head-halves of 4 heads
        int D = Ks[l + 1], dk = D / 8, HD = D / 2;
        float scale = 1.f / sqrtf((float)dk);
        // packed weights: [p][0:HD]=Wq^T half p, [p][HD:D]=Wk^T half p
        transpose_split<<<dim3(D / 32, D / 32), 256, 0, stream>>>(
            qws[l], qkwPh, qkwPl, D, D, HD, (long)D * D, 0, D);
        transpose_split<<<dim3(D / 32, D / 32), 256, 0, stream>>>(
            kws[l], qkwPh, qkwPl, D, D, HD, (long)D * D, HD, D);
        pack_bias2<<<4, 256, 0, stream>>>(qbs[l], kbs[l], qkb, D);

        for (int p = 0; p < 2; ++p) {
            // QK[:,0:HD]=Q(4 heads), QK[:,HD:D]=K(4 heads): one dispatch, N=D.
            qkgemm<<<dim3(128, D / 256), 256, 0, stream>>>(
                xh, xl, qkwPh + (size_t)p * D * D, qkwPl + (size_t)p * D * D,
                qkb + (size_t)p * D, QKh, QKl, pad, D, 1024, D, D);
            if (sc4) {
                // ALL 4 heads of half p in ONE dispatch (zq=head via sA1=dk):
                // 1024 blocks in flight vs 2x512 sequential.
                mgemm<<<dim3(2, 2, 256), 256, 0, stream>>>(
                    QKh, QKl, QKh + HD, QKl + HD,
                    nullptr, scores, nullptr, nullptr, nullptr, nullptr, nullptr, pad,
                    dk, D, D, 256, 0, 64,
                    dk, (long)256 * D, dk, (long)256 * D, (long)64 * 65536, 65536,
                    0, 0, scale, 0, 2, 0);
                softmax_headsum<<<4096, 256, 0, stream>>>(scores, pad, a, p ? 1 : 0, 4);
            } else {
                for (int hp = 0; hp < 2; ++hp) {  // 2 heads per scores dispatch
                    mgemm<<<dim3(2, 2, 128), 256, 0, stream>>>(
                        QKh + (size_t)(hp * 2) * dk, QKl + (size_t)(hp * 2) * dk,
                        QKh + HD + (size_t)(hp * 2) * dk, QKl + HD + (size_t)(hp * 2) * dk,
                        nullptr, scores, nullptr, nullptr, nullptr, nullptr, nullptr, pad,
                        dk, D, D, 256, 0, 64,
                        dk, (long)256 * D, dk, (long)256 * D, (long)64 * 65536, 65536,
                        0, 0, scale, 0, 2, 0);
                    softmax_headsum<<<4096, 256, 0, stream>>>(scores, pad, a, (p * 2 + hp) ? 1 : 0, 2);
                }
            }
        }
        tk_init<<<64, 256, 0, stream>>>(ghist, prefix, krem);
        for (int pp = 0; pp < 4; ++pp) {
            tk_hist<<<1024, 256, 0, stream>>>(a, prefix, ghist, 24 - 8 * pp);
            tk_pick<<<64, 256, 0, stream>>>(ghist, prefix, krem, thr, pp == 3);
        }
        select_apply<<<16384, 256, 0, stream>>>(a, thr, a2h, a2l, denom);
    }
}